// Round 3
// baseline (460.314 us; speedup 1.0000x reference)
//
#include <hip/hip_runtime.h>
#include <hip/hip_bf16.h>

// Problem constants
#define B_SZ 8192
#define D_SZ 512
#define K_SZ 4096
#define L_SZ 16
#define M_ALL (B_SZ + K_SZ)   // 12288 rows: targets stacked over codebook

typedef __attribute__((ext_vector_type(8))) short short8v;      // 8 bf16
typedef __attribute__((ext_vector_type(4))) float f32x4;
typedef _Float16 half8v __attribute__((ext_vector_type(8)));    // 8 fp16 = 16B
typedef _Float16 h2 __attribute__((ext_vector_type(2)));        // packed fp16 pair
struct H2x4 { h2 a, b, c, d; };                                 // = one half8v

typedef const __attribute__((address_space(1))) void gvoid;
typedef __attribute__((address_space(3))) void lvoid;

static __device__ __forceinline__ h2 habs2(h2 a) {
    unsigned u = __builtin_bit_cast(unsigned, a) & 0x7FFF7FFFu;
    return __builtin_bit_cast(h2, u);
}
static __device__ __forceinline__ h2 hmax2(h2 a, h2 b) {
#if __has_builtin(__builtin_elementwise_max)
    return __builtin_elementwise_max(a, b);
#else
    h2 r; r[0] = a[0] > b[0] ? a[0] : b[0]; r[1] = a[1] > b[1] ? a[1] : b[1]; return r;
#endif
}

// ---------------------------------------------------------------------------
// Kernel 1: cast targets+codebook (fp32) into one stacked bf16 matrix [12288 x 512]
// ---------------------------------------------------------------------------
__global__ void cast_bf16_kernel(const float* __restrict__ targets,
                                 const float* __restrict__ codebook,
                                 __hip_bfloat16* __restrict__ abf) {
    int idx = blockIdx.x * blockDim.x + threadIdx.x;
    const int total4 = (M_ALL * D_SZ) / 4;
    if (idx >= total4) return;
    int base = idx * 4;
    const float* src = (base < B_SZ * D_SZ) ? (targets + base)
                                            : (codebook + (base - B_SZ * D_SZ));
    float4 v = *(const float4*)src;
    abf[base + 0] = __float2bfloat16(v.x);
    abf[base + 1] = __float2bfloat16(v.y);
    abf[base + 2] = __float2bfloat16(v.z);
    abf[base + 3] = __float2bfloat16(v.w);
}

// ---------------------------------------------------------------------------
// Kernel 1b: exact fp64 codebook row norms^2 (for algebraic ||r||^2 update)
// ---------------------------------------------------------------------------
__global__ void cn2_kernel(const float* __restrict__ codebook,
                           double* __restrict__ cn2) {
    int row  = blockIdx.x * 4 + (threadIdx.x >> 6);
    int lane = threadIdx.x & 63;
    const float* r = codebook + (size_t)row * D_SZ;
    double s = 0.0;
#pragma unroll
    for (int j = 0; j < 8; j++) { double v = (double)r[lane + 64 * j]; s += v * v; }
#pragma unroll
    for (int o = 32; o > 0; o >>= 1) s += __shfl_down(s, o, 64);
    if (lane == 0) cn2[row] = s;
}

// ---------------------------------------------------------------------------
// Kernel 2: S = A * B^T -> fp16 [M x 4096]. 128x128 tile, 4 waves, 16x16x32
// MFMA. m97-style staging: global_load_lds width=16 into UNPADDED [128][32]
// LDS tiles. EXACT round-0 version (best measured total).
// ---------------------------------------------------------------------------
#define BM 128
#define BN 128
#define BK 32   // bf16 elems: 64 B per LDS row, unpadded

__global__ __launch_bounds__(256)
void gemm_bt_kernel(const __hip_bfloat16* __restrict__ A,
                    const __hip_bfloat16* __restrict__ Bm,
                    _Float16* __restrict__ C) {
    __shared__ short As[BM * BK];   // 8 KB
    __shared__ short Bs[BN * BK];   // 8 KB
    const int tid  = threadIdx.x;
    const int bm   = blockIdx.y * BM;
    const int bn   = blockIdx.x * BN;
    const int wave = tid >> 6, lane = tid & 63;
    const int wm = (wave & 1) * 64, wn = (wave >> 1) * 64;
    const int row16 = lane & 15, quad = lane >> 4;
    const int koff = quad * 8;

    f32x4 acc[4][4] = {};

    const short* Ag = (const short*)A;
    const short* Bg = (const short*)Bm;
    const int srow = lane >> 2;          // 0..15 within a 16-row group
    const int scol = (lane & 3) * 8;     // elem offset 0/8/16/24 (16 B chunks)

    for (int k0 = 0; k0 < D_SZ; k0 += BK) {
        __syncthreads();   // protect previous iteration's fragment reads
#pragma unroll
        for (int c = 0; c < 2; c++) {
            int row = (wave * 2 + c) * 16 + srow;
            __builtin_amdgcn_global_load_lds(
                (gvoid*)(Ag + (size_t)(bm + row) * D_SZ + k0 + scol),
                (lvoid*)(As + row * BK + scol), 16, 0, 0);
            __builtin_amdgcn_global_load_lds(
                (gvoid*)(Bg + (size_t)(bn + row) * D_SZ + k0 + scol),
                (lvoid*)(Bs + row * BK + scol), 16, 0, 0);
        }
        __syncthreads();   // drains vmcnt -> LDS tiles complete

        short8v af[4], bf[4];
#pragma unroll
        for (int i = 0; i < 4; i++)
            af[i] = *(const short8v*)(As + (wm + i * 16 + row16) * BK + koff);
#pragma unroll
        for (int j = 0; j < 4; j++)
            bf[j] = *(const short8v*)(Bs + (wn + j * 16 + row16) * BK + koff);
#pragma unroll
        for (int i = 0; i < 4; i++)
#pragma unroll
            for (int j = 0; j < 4; j++)
                acc[i][j] = __builtin_amdgcn_mfma_f32_16x16x32_bf16(af[i], bf[j], acc[i][j], 0, 0, 0);
    }

    // C/D layout: col = lane&15, row = quad*4 + reg  [m89/m91 verified]
    if (bm < B_SZ) {
        // score region: written once, read once by pursuit -> non-temporal
#pragma unroll
        for (int i = 0; i < 4; i++) {
            int grow = bm + wm + i * 16 + quad * 4;
#pragma unroll
            for (int j = 0; j < 4; j++) {
                int gcol = bn + wn + j * 16 + row16;
#pragma unroll
                for (int r = 0; r < 4; r++)
                    __builtin_nontemporal_store((_Float16)acc[i][j][r],
                                                &C[(size_t)(grow + r) * K_SZ + gcol]);
            }
        }
    } else {
        // Gram region: hot random-access data for pursuit -> keep cached
#pragma unroll
        for (int i = 0; i < 4; i++) {
            int grow = bm + wm + i * 16 + quad * 4;
#pragma unroll
            for (int j = 0; j < 4; j++) {
                int gcol = bn + wn + j * 16 + row16;
#pragma unroll
                for (int r = 0; r < 4; r++)
                    C[(size_t)(grow + r) * K_SZ + gcol] = (_Float16)acc[i][j][r];
            }
        }
    }
}

// ---------------------------------------------------------------------------
// Kernel 3: pursuit. Round-0 LDS structure (proven 208us), but now each wave
// runs TWO independent row-chains interleaved. Rationale: pursuit is
// latency-bound (VALUBusy 50% @ occ 38%; each wave ~85% stalled on the
// serial scan->pick->load->reduce->update chain). Two independent dependency
// graphs per wave double per-wave memory-level parallelism: chain B's loads
// and VALU issue under chain A's stalls. Chains/CU unchanged (2 blocks/CU x
// 4 waves x 2 chains = 16). All per-chain state statically indexed via named
// structs + unrolled loops (round-1 lesson: no dynamic indexing -> no scratch).
// ---------------------------------------------------------------------------
#define MAXC 16
#define MARGIN 1.5f

struct Chain {
    double rres[8];
    double rn2;
    float  m;
    bool   tgt_ok;
    bool   run;
    int    b;
    _Float16* g;   // LDS, 4096 fp16
    int*   cnt;    // LDS
    int*   cand;   // LDS, MAXC
};

struct Step {
    int bk; double bv; bool have_bv;
    float4 c0, c1;
    half8v Gh[8];
};

__device__ __forceinline__ void chain_init(Chain& C, int lane8,
        const float* __restrict__ targets, const _Float16* __restrict__ S) {
    h2 tmax; tmax[0] = (_Float16)0; tmax[1] = (_Float16)0;
    const _Float16* g0 = S + (size_t)C.b * K_SZ + lane8;
#pragma unroll
    for (int c = 0; c < 8; c++) {
        half8v h = __builtin_nontemporal_load((const half8v*)(g0 + c * 512));
        *(half8v*)&C.g[c * 512 + lane8] = h;
        H2x4 u = __builtin_bit_cast(H2x4, h);
        tmax = hmax2(tmax, hmax2(hmax2(habs2(u.a), habs2(u.b)),
                                 hmax2(habs2(u.c), habs2(u.d))));
    }
    C.m = fmaxf((float)tmax[0], (float)tmax[1]);

    const float* tg = targets + (size_t)C.b * D_SZ + lane8;
    f32x4 t0 = __builtin_nontemporal_load((const f32x4*)tg);
    f32x4 t1 = __builtin_nontemporal_load((const f32x4*)(tg + 4));
    C.rres[0] = t0[0]; C.rres[1] = t0[1]; C.rres[2] = t0[2]; C.rres[3] = t0[3];
    C.rres[4] = t1[0]; C.rres[5] = t1[1]; C.rres[6] = t1[2]; C.rres[7] = t1[3];
    double loc = 0.0;
#pragma unroll
    for (int e = 0; e < 8; e++) loc += C.rres[e] * C.rres[e];
#pragma unroll
    for (int o = 32; o > 0; o >>= 1) loc += __shfl_xor(loc, o, 64);
    C.rn2 = loc;
    C.tgt_ok = (sqrt(loc) >= 1e-8);
    C.run = true;
}

// wave max + threshold + candidate collection (cand/cnt in LDS)
__device__ __forceinline__ void chain_scan(Chain& C, int lane, int lane8) {
    float M = C.m;
#pragma unroll
    for (int o = 32; o > 0; o >>= 1) M = fmaxf(M, __shfl_xor(M, o, 64));
    float thr = M - MARGIN;
    if (lane == 0) *C.cnt = 0;
    if (C.m >= thr) {
#pragma unroll
        for (int c = 0; c < 8; c++) {
            half8v h = *(const half8v*)&C.g[c * 512 + lane8];
#pragma unroll
            for (int e = 0; e < 8; e++) {
                float f = fabsf((float)h[e]);
                if (f >= thr) {
                    int q = atomicAdd(C.cnt, 1);
                    if (q < MAXC) C.cand[q] = c * 512 + lane8 + e;
                }
            }
        }
    }
}

// pick winner (nc==1 fast path defers the fp64 dot) + ISSUE all loads
__device__ __forceinline__ void chain_pick(Chain& C, Step& st, int nc, int lane8,
        const float* __restrict__ codebook, const _Float16* __restrict__ S) {
    if (nc == 1) {
        st.bk = __builtin_amdgcn_readfirstlane(C.cand[0]);
        st.have_bv = false;
        const float* cr = codebook + (size_t)st.bk * D_SZ + lane8;
        const _Float16* Gp = S + (size_t)(B_SZ + st.bk) * K_SZ + lane8;
        st.c0 = *(const float4*)cr;
        st.c1 = *(const float4*)(cr + 4);
#pragma unroll
        for (int c = 0; c < 8; c++) st.Gh[c] = *(const half8v*)(Gp + c * 512);
    } else {
        int bk = -1; double bv = 0.0;
        for (int ci = 0; ci < nc; ci++) {
            int k = __builtin_amdgcn_readfirstlane(C.cand[ci]);
            const float* cr = codebook + (size_t)k * D_SZ + lane8;
            float4 d0 = *(const float4*)cr;
            float4 d1 = *(const float4*)(cr + 4);
            double s = C.rres[0] * (double)d0.x + C.rres[1] * (double)d0.y
                     + C.rres[2] * (double)d0.z + C.rres[3] * (double)d0.w
                     + C.rres[4] * (double)d1.x + C.rres[5] * (double)d1.y
                     + C.rres[6] * (double)d1.z + C.rres[7] * (double)d1.w;
#pragma unroll
            for (int o = 32; o > 0; o >>= 1) s += __shfl_xor(s, o, 64);
            if (bk < 0 || fabs(s) > fabs(bv) ||
                (fabs(s) == fabs(bv) && k < bk)) { bk = k; bv = s; }
        }
        st.bk = bk; st.bv = bv; st.have_bv = true;
        const float* cr = codebook + (size_t)bk * D_SZ + lane8;
        const _Float16* Gp = S + (size_t)(B_SZ + bk) * K_SZ + lane8;
        st.c0 = *(const float4*)cr;
        st.c1 = *(const float4*)(cr + 4);
#pragma unroll
        for (int c = 0; c < 8; c++) st.Gh[c] = *(const half8v*)(Gp + c * 512);
    }
}

// fp64 dot + reduce for the nc==1 fast path
__device__ __forceinline__ void chain_dot(Chain& C, Step& st) {
    if (!st.have_bv) {
        double s = C.rres[0] * (double)st.c0.x + C.rres[1] * (double)st.c0.y
                 + C.rres[2] * (double)st.c0.z + C.rres[3] * (double)st.c0.w
                 + C.rres[4] * (double)st.c1.x + C.rres[5] * (double)st.c1.y
                 + C.rres[6] * (double)st.c1.z + C.rres[7] * (double)st.c1.w;
#pragma unroll
        for (int o = 32; o > 0; o >>= 1) s += __shfl_xor(s, o, 64);
        st.bv = s;
    }
}

// decision + outputs + fused g update + diag patch + rres update
__device__ __forceinline__ void chain_finish(Chain& C, Step& st, double decay, int t,
        int lane, int lane8, const double* __restrict__ cn2,
        float* out_seq, float* out_mask) {
    const double cn2bk = cn2[st.bk];
    double sd = ((st.bv >= 0.0) ? 1.0 : -1.0) * decay;
    C.rn2 = C.rn2 - 2.0 * sd * st.bv + sd * sd * cn2bk;
    if (lane == 0) {
        __builtin_nontemporal_store((float)((st.bv >= 0.0) ? st.bk : (-st.bk - 1)), &out_seq[t]);
        __builtin_nontemporal_store(1.0f, &out_mask[t]);
    }
    const float sdf = (float)sd;
    h2 sdh2; sdh2[0] = (_Float16)sdf; sdh2[1] = (_Float16)sdf;

    h2 tmax; tmax[0] = (_Float16)0; tmax[1] = (_Float16)0;
#pragma unroll
    for (int c = 0; c < 8; c++) {
        half8v gv = *(const half8v*)&C.g[c * 512 + lane8];
        H2x4 ug = __builtin_bit_cast(H2x4, gv);
        H2x4 uG = __builtin_bit_cast(H2x4, st.Gh[c]);
        ug.a -= sdh2 * uG.a; ug.b -= sdh2 * uG.b;
        ug.c -= sdh2 * uG.c; ug.d -= sdh2 * uG.d;
        *(half8v*)&C.g[c * 512 + lane8] = __builtin_bit_cast(half8v, ug);
        tmax = hmax2(tmax, hmax2(hmax2(habs2(ug.a), habs2(ug.b)),
                                 hmax2(habs2(ug.c), habs2(ug.d))));
    }
    C.m = fmaxf((float)tmax[0], (float)tmax[1]);

    // exact diagonal patch (MARGIN covers <=0.5 lane-max staleness)
    if (lane == 0) C.g[st.bk] = (_Float16)(float)(st.bv - sd * cn2bk);

    C.rres[0] -= sd * (double)st.c0.x; C.rres[1] -= sd * (double)st.c0.y;
    C.rres[2] -= sd * (double)st.c0.z; C.rres[3] -= sd * (double)st.c0.w;
    C.rres[4] -= sd * (double)st.c1.x; C.rres[5] -= sd * (double)st.c1.y;
    C.rres[6] -= sd * (double)st.c1.z; C.rres[7] -= sd * (double)st.c1.w;
}

__global__ __launch_bounds__(256, 2)
void pursuit_kernel(const float* __restrict__ targets,
                    const float* __restrict__ codebook,
                    const _Float16* __restrict__ S,   // [12288 x 4096]; rows >=8192 are Gram
                    const double* __restrict__ cn2,   // [4096] exact ||c_k||^2
                    float* __restrict__ out) {
    const int wave = threadIdx.x >> 6;
    const int lane = threadIdx.x & 63;
    const int lane8 = lane * 8;

    __shared__ alignas(16) _Float16 g_s[8][K_SZ];   // 64 KB: 4 waves x 2 chains
    __shared__ int s_cnt[8];
    __shared__ int s_cand[8][MAXC];

    Chain A, Bc;
    A.b  = blockIdx.x * 8 + wave * 2;
    Bc.b = A.b + 1;
    A.g  = g_s[wave * 2 + 0];  Bc.g  = g_s[wave * 2 + 1];
    A.cnt  = &s_cnt[wave * 2 + 0];  Bc.cnt  = &s_cnt[wave * 2 + 1];
    A.cand = s_cand[wave * 2 + 0];  Bc.cand = s_cand[wave * 2 + 1];

    chain_init(A,  lane8, targets, S);
    chain_init(Bc, lane8, targets, S);

    float* outA_seq  = out + (size_t)A.b * L_SZ;
    float* outA_mask = out + (size_t)B_SZ * L_SZ + (size_t)A.b * L_SZ;
    float* outA_res  = out + (size_t)2 * B_SZ * L_SZ + (size_t)A.b * D_SZ;
    float* outB_seq  = out + (size_t)Bc.b * L_SZ;
    float* outB_mask = out + (size_t)B_SZ * L_SZ + (size_t)Bc.b * L_SZ;
    float* outB_res  = out + (size_t)2 * B_SZ * L_SZ + (size_t)Bc.b * D_SZ;

    double decay = 1.0;

    for (int t = 0; t < L_SZ; t++) {
        decay *= 0.95;
        if (A.run) {
            bool act = (sqrt(A.rn2) >= 0.01) && A.tgt_ok;   // wave-uniform
            if (!act) {
                if (lane == 0)
                    for (int tt = t; tt < L_SZ; tt++) {
                        __builtin_nontemporal_store(0.0f, &outA_seq[tt]);
                        __builtin_nontemporal_store(0.0f, &outA_mask[tt]);
                    }
                A.run = false;
            }
        }
        if (Bc.run) {
            bool act = (sqrt(Bc.rn2) >= 0.01) && Bc.tgt_ok;
            if (!act) {
                if (lane == 0)
                    for (int tt = t; tt < L_SZ; tt++) {
                        __builtin_nontemporal_store(0.0f, &outB_seq[tt]);
                        __builtin_nontemporal_store(0.0f, &outB_mask[tt]);
                    }
                Bc.run = false;
            }
        }
        if (!A.run && !Bc.run) break;

        // interleaved phases: both chains' scans, then both picks (loads in
        // flight for both), then both dots, then both finishes.
        if (A.run)  chain_scan(A,  lane, lane8);
        if (Bc.run) chain_scan(Bc, lane, lane8);
        __threadfence_block();
        int ncA = A.run  ? min(*A.cnt,  MAXC) : 0;
        int ncB = Bc.run ? min(*Bc.cnt, MAXC) : 0;

        Step sA, sB;
        if (A.run)  chain_pick(A,  sA, ncA, lane8, codebook, S);
        if (Bc.run) chain_pick(Bc, sB, ncB, lane8, codebook, S);
        if (A.run)  chain_dot(A,  sA);
        if (Bc.run) chain_dot(Bc, sB);
        if (A.run)  chain_finish(A,  sA, decay, t, lane, lane8, cn2, outA_seq, outA_mask);
        if (Bc.run) chain_finish(Bc, sB, decay, t, lane, lane8, cn2, outB_seq, outB_mask);
    }

    // ---- final residuals (non-temporal) ----
    {
        f32x4 r0, r1;
        r0[0] = (float)A.rres[0]; r0[1] = (float)A.rres[1]; r0[2] = (float)A.rres[2]; r0[3] = (float)A.rres[3];
        r1[0] = (float)A.rres[4]; r1[1] = (float)A.rres[5]; r1[2] = (float)A.rres[6]; r1[3] = (float)A.rres[7];
        __builtin_nontemporal_store(r0, (f32x4*)(outA_res + lane8));
        __builtin_nontemporal_store(r1, (f32x4*)(outA_res + lane8 + 4));
        r0[0] = (float)Bc.rres[0]; r0[1] = (float)Bc.rres[1]; r0[2] = (float)Bc.rres[2]; r0[3] = (float)Bc.rres[3];
        r1[0] = (float)Bc.rres[4]; r1[1] = (float)Bc.rres[5]; r1[2] = (float)Bc.rres[6]; r1[3] = (float)Bc.rres[7];
        __builtin_nontemporal_store(r0, (f32x4*)(outB_res + lane8));
        __builtin_nontemporal_store(r1, (f32x4*)(outB_res + lane8 + 4));
    }
}

// ---------------------------------------------------------------------------
extern "C" void kernel_launch(void* const* d_in, const int* in_sizes, int n_in,
                              void* d_out, int out_size, void* d_ws, size_t ws_size,
                              hipStream_t stream) {
    const float* targets  = (const float*)d_in[0];
    const float* codebook = (const float*)d_in[1];
    float* out = (float*)d_out;

    __hip_bfloat16* abf = (__hip_bfloat16*)d_ws;                         // 12,582,912 B
    _Float16* S = (_Float16*)((char*)d_ws + (size_t)M_ALL * D_SZ * 2);   // 100,663,296 B
    double* cn2 = (double*)((char*)d_ws + (size_t)M_ALL * D_SZ * 2
                                        + (size_t)M_ALL * K_SZ * 2);     // 32,768 B
    // total ws needed: ~113.3 MB

    int total4 = (M_ALL * D_SZ) / 4;
    cast_bf16_kernel<<<(total4 + 255) / 256, 256, 0, stream>>>(targets, codebook, abf);
    cn2_kernel<<<K_SZ / 4, 256, 0, stream>>>(codebook, cn2);

    dim3 ggrid(K_SZ / BN, M_ALL / BM);
    gemm_bt_kernel<<<ggrid, 256, 0, stream>>>(abf, abf + (size_t)B_SZ * D_SZ, S);

    pursuit_kernel<<<B_SZ / 8, 256, 0, stream>>>(targets, codebook, S, cn2, out);
}

// Round 5
// 345.243 us; speedup vs baseline: 1.3333x; 1.3333x over previous
//
#include <hip/hip_runtime.h>
#include <hip/hip_bf16.h>

// Problem constants
#define B_SZ 8192
#define D_SZ 512
#define K_SZ 4096
#define L_SZ 16
#define M_ALL (B_SZ + K_SZ)   // 12288 rows: targets stacked over codebook

typedef __attribute__((ext_vector_type(8))) short short8v;      // 8 bf16
typedef __attribute__((ext_vector_type(4))) float f32x4;
typedef _Float16 half8v __attribute__((ext_vector_type(8)));    // 8 fp16 = 16B
typedef _Float16 half4v __attribute__((ext_vector_type(4)));    // 4 fp16 = 8B
typedef _Float16 h2 __attribute__((ext_vector_type(2)));        // packed fp16 pair
struct H2x4 { h2 a, b, c, d; };                                 // = one half8v

typedef const __attribute__((address_space(1))) void gvoid;
typedef __attribute__((address_space(3))) void lvoid;

static __device__ __forceinline__ h2 habs2(h2 a) {
    unsigned u = __builtin_bit_cast(unsigned, a) & 0x7FFF7FFFu;
    return __builtin_bit_cast(h2, u);
}
static __device__ __forceinline__ h2 hmax2(h2 a, h2 b) {
#if __has_builtin(__builtin_elementwise_max)
    return __builtin_elementwise_max(a, b);
#else
    h2 r; r[0] = a[0] > b[0] ? a[0] : b[0]; r[1] = a[1] > b[1] ? a[1] : b[1]; return r;
#endif
}

// ---------------------------------------------------------------------------
// Kernel 1: cast targets+codebook (fp32) into one stacked bf16 matrix [12288 x 512]
// ---------------------------------------------------------------------------
__global__ void cast_bf16_kernel(const float* __restrict__ targets,
                                 const float* __restrict__ codebook,
                                 __hip_bfloat16* __restrict__ abf) {
    int idx = blockIdx.x * blockDim.x + threadIdx.x;
    const int total4 = (M_ALL * D_SZ) / 4;
    if (idx >= total4) return;
    int base = idx * 4;
    const float* src = (base < B_SZ * D_SZ) ? (targets + base)
                                            : (codebook + (base - B_SZ * D_SZ));
    float4 v = *(const float4*)src;
    abf[base + 0] = __float2bfloat16(v.x);
    abf[base + 1] = __float2bfloat16(v.y);
    abf[base + 2] = __float2bfloat16(v.z);
    abf[base + 3] = __float2bfloat16(v.w);
}

// ---------------------------------------------------------------------------
// Kernel 1b: exact fp64 codebook row norms^2 (for algebraic ||r||^2 update)
// ---------------------------------------------------------------------------
__global__ void cn2_kernel(const float* __restrict__ codebook,
                           double* __restrict__ cn2) {
    int row  = blockIdx.x * 4 + (threadIdx.x >> 6);
    int lane = threadIdx.x & 63;
    const float* r = codebook + (size_t)row * D_SZ;
    double s = 0.0;
#pragma unroll
    for (int j = 0; j < 8; j++) { double v = (double)r[lane + 64 * j]; s += v * v; }
#pragma unroll
    for (int o = 32; o > 0; o >>= 1) s += __shfl_down(s, o, 64);
    if (lane == 0) cn2[row] = s;
}

// ---------------------------------------------------------------------------
// Kernel 2: S = A * B^T -> fp16 [M x 4096]. 128x128 tile, 4 waves, 16x16x32
// MFMA. Changes vs round-0 (both targeting the short-K overheads):
//  * BK=64: 8 K-steps instead of 16 -> half the vmcnt(0)+barrier drains,
//    32 MFMA per barrier. 128 B LDS rows would put 4 quads on 16 banks
//    (2x read cost), so chunk-XOR swizzle: LDS stays LINEAR (required by
//    global_load_lds), the GLOBAL source chunk is pre-permuted with
//    chunk = (lane&7)^(row&7), and reads use slot = kc^(row&7).
//    Involution check: slot s holds global chunk s^(r&7); reading chunk kc
//    at slot kc^(r&7) returns (kc^(r&7))^(r&7) = kc.  8 rows -> 8 distinct
//    4-bank groups -> all 32 banks, 2 lanes/bank (free).
//  * Operand-swap + packed epilogue (harness-verified in round 2):
//    acc = mfma(bf, af, acc) -> C/D frag holds 4 consecutive N-columns
//    (row = lane&15, col = quad*4 + reg) -> one 8 B half4v store per (i,j):
//    16 store insts/thread instead of 64 scalar b16 stores.
// Score-region output (rows < 8192, read once) stored non-temporal so the
// 32 MiB Gram region stays L3-resident for the pursuit kernel.
// ---------------------------------------------------------------------------
#define BM 128
#define BN 128
#define BK 64   // bf16 elems: 128 B per LDS row, 8 chunks of 16 B

__global__ __launch_bounds__(256)
void gemm_bt_kernel(const __hip_bfloat16* __restrict__ A,
                    const __hip_bfloat16* __restrict__ Bm,
                    _Float16* __restrict__ C) {
    __shared__ short As[BM * BK];   // 16 KB
    __shared__ short Bs[BN * BK];   // 16 KB
    const int tid  = threadIdx.x;
    const int bm   = blockIdx.y * BM;
    const int bn   = blockIdx.x * BN;
    const int wave = tid >> 6, lane = tid & 63;
    const int wm = (wave & 1) * 64, wn = (wave >> 1) * 64;
    const int row16 = lane & 15, quad = lane >> 4;

    f32x4 acc[4][4] = {};

    const short* Ag = (const short*)A;
    const short* Bg = (const short*)Bm;

    // staging geometry: per inst, one wave covers 8 rows x 8 chunks (1 KB)
    const int lrow  = lane >> 3;          // 0..7 row within 8-row group
    const int lchk  = lane & 7;           // LDS slot 0..7 (16 B chunks)

    for (int k0 = 0; k0 < D_SZ; k0 += BK) {
        __syncthreads();   // protect previous iteration's fragment reads
#pragma unroll
        for (int c = 0; c < 4; c++) {
            const int rbase = (wave * 4 + c) * 8;     // 0,8,...,120
            const int row   = rbase + lrow;
            const int schunk = lchk ^ (row & 7);      // pre-swizzled global chunk
            // LDS dest linear: base + lane*16B  (wave-uniform base rbase*BK)
            __builtin_amdgcn_global_load_lds(
                (gvoid*)(Ag + (size_t)(bm + row) * D_SZ + k0 + schunk * 8),
                (lvoid*)(As + row * BK + lchk * 8), 16, 0, 0);
            __builtin_amdgcn_global_load_lds(
                (gvoid*)(Bg + (size_t)(bn + row) * D_SZ + k0 + schunk * 8),
                (lvoid*)(Bs + row * BK + lchk * 8), 16, 0, 0);
        }
        __syncthreads();   // drains vmcnt -> LDS tiles complete

#pragma unroll
        for (int kh = 0; kh < 2; kh++) {
            short8v af[4], bf[4];
#pragma unroll
            for (int i = 0; i < 4; i++) {
                int row = wm + i * 16 + row16;
                int slot = (kh * 4 + quad) ^ (row & 7);
                af[i] = *(const short8v*)(As + row * BK + slot * 8);
            }
#pragma unroll
            for (int j = 0; j < 4; j++) {
                int row = wn + j * 16 + row16;
                int slot = (kh * 4 + quad) ^ (row & 7);
                bf[j] = *(const short8v*)(Bs + row * BK + slot * 8);
            }
            // swapped operand order -> transposed C/D fragment (R2-verified)
#pragma unroll
            for (int i = 0; i < 4; i++)
#pragma unroll
                for (int j = 0; j < 4; j++)
                    acc[i][j] = __builtin_amdgcn_mfma_f32_16x16x32_bf16(bf[j], af[i], acc[i][j], 0, 0, 0);
        }
    }

    // Swapped C/D layout: row(A-dim) = lane&15, col(B-dim) = quad*4 + reg.
    const int grow0 = bm + wm + row16;
    const int gcol0 = bn + wn + quad * 4;
    if (bm < B_SZ) {
        // score region: written once, read once by pursuit -> non-temporal
#pragma unroll
        for (int i = 0; i < 4; i++) {
            size_t rbase = (size_t)(grow0 + i * 16) * K_SZ;
#pragma unroll
            for (int j = 0; j < 4; j++) {
                half4v p;
                p[0] = (_Float16)acc[i][j][0]; p[1] = (_Float16)acc[i][j][1];
                p[2] = (_Float16)acc[i][j][2]; p[3] = (_Float16)acc[i][j][3];
                __builtin_nontemporal_store(p, (half4v*)&C[rbase + gcol0 + j * 16]);
            }
        }
    } else {
        // Gram region: hot random-access data for pursuit -> keep cached
#pragma unroll
        for (int i = 0; i < 4; i++) {
            size_t rbase = (size_t)(grow0 + i * 16) * K_SZ;
#pragma unroll
            for (int j = 0; j < 4; j++) {
                half4v p;
                p[0] = (_Float16)acc[i][j][0]; p[1] = (_Float16)acc[i][j][1];
                p[2] = (_Float16)acc[i][j][2]; p[3] = (_Float16)acc[i][j][3];
                *(half4v*)&C[rbase + gcol0 + j * 16] = p;
            }
        }
    }
}

// ---------------------------------------------------------------------------
// Kernel 3: pursuit, wave-per-row, g in LDS as fp16 (8 KB/row, linear,
// conflict-free b128). EXACT round-0 version (best measured: 208 us).
// Latency/concurrency-bound at ~2.86 TB/s effective on 554 MB fetch; three
// structural variants (reg-g, 2-wave blocks, 2-chain waves) all regressed.
// ---------------------------------------------------------------------------
#define MAXC 16
#define MARGIN 1.5f

__global__ __launch_bounds__(256, 4)
void pursuit_kernel(const float* __restrict__ targets,
                    const float* __restrict__ codebook,
                    const _Float16* __restrict__ S,   // [12288 x 4096]; rows >=8192 are Gram
                    const double* __restrict__ cn2,   // [4096] exact ||c_k||^2
                    float* __restrict__ out) {
    const int wave = threadIdx.x >> 6;
    const int lane = threadIdx.x & 63;
    const int b = blockIdx.x * 4 + wave;
    const int lane8 = lane * 8;

    __shared__ alignas(16) _Float16 g_s[4][K_SZ];
    __shared__ int s_cnt[4];
    __shared__ int s_cand[4][MAXC];
    _Float16* g = g_s[wave];
    int* cnt  = &s_cnt[wave];
    int* cand = s_cand[wave];

    // ---- init: score row -> LDS (non-temporal), lane max in flight ----
    h2 tmax; tmax[0] = (_Float16)0; tmax[1] = (_Float16)0;
    {
        const _Float16* g0 = S + (size_t)b * K_SZ + lane8;
#pragma unroll
        for (int c = 0; c < 8; c++) {
            half8v h = __builtin_nontemporal_load((const half8v*)(g0 + c * 512));
            *(half8v*)&g[c * 512 + lane8] = h;
            H2x4 u = __builtin_bit_cast(H2x4, h);
            tmax = hmax2(tmax, hmax2(hmax2(habs2(u.a), habs2(u.b)),
                                     hmax2(habs2(u.c), habs2(u.d))));
        }
    }
    float m = fmaxf((float)tmax[0], (float)tmax[1]);

    // ---- lane-private fp64 residual + tn2 (non-temporal target read) ----
    double rres[8];
    double loc = 0.0;
    {
        const float* tg = targets + (size_t)b * D_SZ + lane8;
        f32x4 t0 = __builtin_nontemporal_load((const f32x4*)tg);
        f32x4 t1 = __builtin_nontemporal_load((const f32x4*)(tg + 4));
        rres[0] = t0[0]; rres[1] = t0[1]; rres[2] = t0[2]; rres[3] = t0[3];
        rres[4] = t1[0]; rres[5] = t1[1]; rres[6] = t1[2]; rres[7] = t1[3];
#pragma unroll
        for (int e = 0; e < 8; e++) loc += rres[e] * rres[e];
    }
#pragma unroll
    for (int o = 32; o > 0; o >>= 1) loc += __shfl_xor(loc, o, 64);
    double rn2 = loc;
    const bool tgt_ok = (sqrt(loc) >= 1e-8);

    float* out_seq  = out + (size_t)b * L_SZ;
    float* out_mask = out + (size_t)B_SZ * L_SZ + (size_t)b * L_SZ;
    float* out_res  = out + (size_t)2 * B_SZ * L_SZ + (size_t)b * D_SZ;

    double decay = 1.0;

    for (int t = 0; t < L_SZ; t++) {
        decay *= 0.95;
        bool active = (sqrt(rn2) >= 0.01) && tgt_ok;   // wave-uniform
        if (!active) {                                 // stays inactive forever
            if (lane == 0)
                for (int tt = t; tt < L_SZ; tt++) {
                    __builtin_nontemporal_store(0.0f, &out_seq[tt]);
                    __builtin_nontemporal_store(0.0f, &out_mask[tt]);
                }
            break;
        }

        // ---- wave max + threshold ----
        float M = m;
#pragma unroll
        for (int o = 32; o > 0; o >>= 1) M = fmaxf(M, __shfl_xor(M, o, 64));
        float thr = M - MARGIN;

        // ---- candidate collection: re-read LDS under divergent guard ----
        if (lane == 0) *cnt = 0;
        if (m >= thr) {
#pragma unroll
            for (int c = 0; c < 8; c++) {
                half8v h = *(const half8v*)&g[c * 512 + lane8];
#pragma unroll
                for (int e = 0; e < 8; e++) {
                    float f = fabsf((float)h[e]);
                    if (f >= thr) {
                        int q = atomicAdd(cnt, 1);
                        if (q < MAXC) cand[q] = c * 512 + lane8 + e;
                    }
                }
            }
        }
        __threadfence_block();
        int nc = min(*cnt, MAXC);

        // ---- exact fp64 rescore; Gram loads hoisted off the tail ----
        int bk; double bv;
        float4 c0, c1;
        half8v Gh[8];
        if (nc == 1) {
            bk = __builtin_amdgcn_readfirstlane(cand[0]);
            const float* cr = codebook + (size_t)bk * D_SZ + lane8;
            const _Float16* Gp = S + (size_t)(B_SZ + bk) * K_SZ + lane8;
            c0 = *(const float4*)cr;
            c1 = *(const float4*)(cr + 4);
#pragma unroll
            for (int c = 0; c < 8; c++) Gh[c] = *(const half8v*)(Gp + c * 512);
            double s = rres[0] * (double)c0.x + rres[1] * (double)c0.y
                     + rres[2] * (double)c0.z + rres[3] * (double)c0.w
                     + rres[4] * (double)c1.x + rres[5] * (double)c1.y
                     + rres[6] * (double)c1.z + rres[7] * (double)c1.w;
#pragma unroll
            for (int o = 32; o > 0; o >>= 1) s += __shfl_xor(s, o, 64);
            bv = s;
        } else {
            bk = -1; bv = 0.0;
            for (int ci = 0; ci < nc; ci++) {
                int k = __builtin_amdgcn_readfirstlane(cand[ci]);
                const float* cr = codebook + (size_t)k * D_SZ + lane8;
                float4 d0 = *(const float4*)cr;
                float4 d1 = *(const float4*)(cr + 4);
                double s = rres[0] * (double)d0.x + rres[1] * (double)d0.y
                         + rres[2] * (double)d0.z + rres[3] * (double)d0.w
                         + rres[4] * (double)d1.x + rres[5] * (double)d1.y
                         + rres[6] * (double)d1.z + rres[7] * (double)d1.w;
#pragma unroll
                for (int o = 32; o > 0; o >>= 1) s += __shfl_xor(s, o, 64);
                if (bk < 0 || fabs(s) > fabs(bv) ||
                    (fabs(s) == fabs(bv) && k < bk)) { bk = k; bv = s; }
            }
            const float* cr = codebook + (size_t)bk * D_SZ + lane8;   // winner row
            const _Float16* Gp = S + (size_t)(B_SZ + bk) * K_SZ + lane8;
            c0 = *(const float4*)cr;
            c1 = *(const float4*)(cr + 4);
#pragma unroll
            for (int c = 0; c < 8; c++) Gh[c] = *(const half8v*)(Gp + c * 512);
        }

        // ---- decision + exact ||r||^2 identity + outputs ----
        const double cn2bk = cn2[bk];
        double sd = ((bv >= 0.0) ? 1.0 : -1.0) * decay;
        rn2 = rn2 - 2.0 * sd * bv + sd * sd * cn2bk;
        if (lane == 0) {
            __builtin_nontemporal_store((float)((bv >= 0.0) ? bk : (-bk - 1)), &out_seq[t]);
            __builtin_nontemporal_store(1.0f, &out_mask[t]);
        }
        const float sdf = (float)sd;
        h2 sdh2; sdh2[0] = (_Float16)sdf; sdh2[1] = (_Float16)sdf;

        // ---- fused g update (LDS RMW) + next-step lane max ----
        tmax[0] = (_Float16)0; tmax[1] = (_Float16)0;
#pragma unroll
        for (int c = 0; c < 8; c++) {
            half8v gv = *(const half8v*)&g[c * 512 + lane8];
            H2x4 ug = __builtin_bit_cast(H2x4, gv);
            H2x4 uG = __builtin_bit_cast(H2x4, Gh[c]);
            ug.a -= sdh2 * uG.a; ug.b -= sdh2 * uG.b;
            ug.c -= sdh2 * uG.c; ug.d -= sdh2 * uG.d;
            *(half8v*)&g[c * 512 + lane8] = __builtin_bit_cast(half8v, ug);
            tmax = hmax2(tmax, hmax2(hmax2(habs2(ug.a), habs2(ug.b)),
                                     hmax2(habs2(ug.c), habs2(ug.d))));
        }
        m = fmaxf((float)tmax[0], (float)tmax[1]);

        // ---- exact diagonal patch: g[bk] := fp16(bv - sd*||c_bk||^2).
        //      m may be stale-high by <=0.5 on one lane; MARGIN=1.5 covers it,
        //      and the candidate re-read above sees the patched value. ----
        if (lane == 0) g[bk] = (_Float16)(float)(bv - sd * cn2bk);

        // ---- exact fp64 residual update (winner row already in regs) ----
        rres[0] -= sd * (double)c0.x; rres[1] -= sd * (double)c0.y;
        rres[2] -= sd * (double)c0.z; rres[3] -= sd * (double)c0.w;
        rres[4] -= sd * (double)c1.x; rres[5] -= sd * (double)c1.y;
        rres[6] -= sd * (double)c1.z; rres[7] -= sd * (double)c1.w;
    }

    // ---- final residual (non-temporal) ----
    {
        f32x4 r0, r1;
        r0[0] = (float)rres[0]; r0[1] = (float)rres[1]; r0[2] = (float)rres[2]; r0[3] = (float)rres[3];
        r1[0] = (float)rres[4]; r1[1] = (float)rres[5]; r1[2] = (float)rres[6]; r1[3] = (float)rres[7];
        __builtin_nontemporal_store(r0, (f32x4*)(out_res + lane8));
        __builtin_nontemporal_store(r1, (f32x4*)(out_res + lane8 + 4));
    }
}

// ---------------------------------------------------------------------------
extern "C" void kernel_launch(void* const* d_in, const int* in_sizes, int n_in,
                              void* d_out, int out_size, void* d_ws, size_t ws_size,
                              hipStream_t stream) {
    const float* targets  = (const float*)d_in[0];
    const float* codebook = (const float*)d_in[1];
    float* out = (float*)d_out;

    __hip_bfloat16* abf = (__hip_bfloat16*)d_ws;                         // 12,582,912 B
    _Float16* S = (_Float16*)((char*)d_ws + (size_t)M_ALL * D_SZ * 2);   // 100,663,296 B
    double* cn2 = (double*)((char*)d_ws + (size_t)M_ALL * D_SZ * 2
                                        + (size_t)M_ALL * K_SZ * 2);     // 32,768 B
    // total ws needed: ~113.3 MB

    int total4 = (M_ALL * D_SZ) / 4;
    cast_bf16_kernel<<<(total4 + 255) / 256, 256, 0, stream>>>(targets, codebook, abf);
    cn2_kernel<<<K_SZ / 4, 256, 0, stream>>>(codebook, cn2);

    dim3 ggrid(K_SZ / BN, M_ALL / BM);
    gemm_bt_kernel<<<ggrid, 256, 0, stream>>>(abf, abf + (size_t)B_SZ * D_SZ, S);

    pursuit_kernel<<<B_SZ / 4, 256, 0, stream>>>(targets, codebook, S, cn2, out);
}

// Round 6
// 334.221 us; speedup vs baseline: 1.3773x; 1.0330x over previous
//
#include <hip/hip_runtime.h>
#include <hip/hip_bf16.h>

// Problem constants
#define B_SZ 8192
#define D_SZ 512
#define K_SZ 4096
#define L_SZ 16
#define M_ALL (B_SZ + K_SZ)   // 12288 rows: targets stacked over codebook

typedef __attribute__((ext_vector_type(8))) short short8v;      // 8 bf16
typedef __attribute__((ext_vector_type(4))) float f32x4;
typedef _Float16 half8v __attribute__((ext_vector_type(8)));    // 8 fp16 = 16B
typedef _Float16 h2 __attribute__((ext_vector_type(2)));        // packed fp16 pair
struct H2x4 { h2 a, b, c, d; };                                 // = one half8v

typedef const __attribute__((address_space(1))) void gvoid;
typedef __attribute__((address_space(3))) void lvoid;

static __device__ __forceinline__ h2 habs2(h2 a) {
    unsigned u = __builtin_bit_cast(unsigned, a) & 0x7FFF7FFFu;
    return __builtin_bit_cast(h2, u);
}
static __device__ __forceinline__ h2 hmax2(h2 a, h2 b) {
#if __has_builtin(__builtin_elementwise_max)
    return __builtin_elementwise_max(a, b);
#else
    h2 r; r[0] = a[0] > b[0] ? a[0] : b[0]; r[1] = a[1] > b[1] ? a[1] : b[1]; return r;
#endif
}

// ---------------------------------------------------------------------------
// Kernel 1: cast targets+codebook (fp32) into one stacked bf16 matrix [12288 x 512]
// ---------------------------------------------------------------------------
__global__ void cast_bf16_kernel(const float* __restrict__ targets,
                                 const float* __restrict__ codebook,
                                 __hip_bfloat16* __restrict__ abf) {
    int idx = blockIdx.x * blockDim.x + threadIdx.x;
    const int total4 = (M_ALL * D_SZ) / 4;
    if (idx >= total4) return;
    int base = idx * 4;
    const float* src = (base < B_SZ * D_SZ) ? (targets + base)
                                            : (codebook + (base - B_SZ * D_SZ));
    float4 v = *(const float4*)src;
    abf[base + 0] = __float2bfloat16(v.x);
    abf[base + 1] = __float2bfloat16(v.y);
    abf[base + 2] = __float2bfloat16(v.z);
    abf[base + 3] = __float2bfloat16(v.w);
}

// ---------------------------------------------------------------------------
// Kernel 1b: exact fp64 codebook row norms^2 (for algebraic ||r||^2 update)
// ---------------------------------------------------------------------------
__global__ void cn2_kernel(const float* __restrict__ codebook,
                           double* __restrict__ cn2) {
    int row  = blockIdx.x * 4 + (threadIdx.x >> 6);
    int lane = threadIdx.x & 63;
    const float* r = codebook + (size_t)row * D_SZ;
    double s = 0.0;
#pragma unroll
    for (int j = 0; j < 8; j++) { double v = (double)r[lane + 64 * j]; s += v * v; }
#pragma unroll
    for (int o = 32; o > 0; o >>= 1) s += __shfl_down(s, o, 64);
    if (lane == 0) cn2[row] = s;
}

// ---------------------------------------------------------------------------
// Kernel 2: S = A * B^T -> fp16 [M x 4096]. 256x128 tile, EIGHT waves
// (512 threads), BK=32, 16x16x32 MFMA, m97-style global_load_lds staging.
// Rationale (round-6): GEMM was ~470 TF -- per-block-iteration barrier-drain
// dominated at K=512.  BM 128->256 with 8 waves HALVES total block-iterations
// (1536x16 vs 3072x16 drains) while keeping EVERY per-wave resource identical
// to the proven m97 shape (64x64 output, 4x4 f32x4 acc, same fragment reads;
// per-wave staging drops 4->3 loads/iter).  LDS 24 KB -> 2 blocks/CU = 16
// waves/CU, same occupancy as round-0.  (m112's 256-tile regression came
// from 4-wave configs doubling per-wave acc; this keeps waves constant.)
// Inner loop / epilogue / layout otherwise IDENTICAL to round-0.
// ---------------------------------------------------------------------------
#define BM 256
#define BN 128
#define BK 32   // bf16 elems: 64 B per LDS row, unpadded

__global__ __launch_bounds__(512)
void gemm_bt_kernel(const __hip_bfloat16* __restrict__ A,
                    const __hip_bfloat16* __restrict__ Bm,
                    _Float16* __restrict__ C) {
    __shared__ short As[BM * BK];   // 16 KB
    __shared__ short Bs[BN * BK];   // 8 KB
    const int tid  = threadIdx.x;
    const int bm   = blockIdx.y * BM;
    const int bn   = blockIdx.x * BN;
    const int wave = tid >> 6, lane = tid & 63;
    const int wm = (wave >> 1) * 64;     // 0,64,128,192
    const int wn = (wave & 1) * 64;      // 0,64
    const int row16 = lane & 15, quad = lane >> 4;
    const int koff = quad * 8;

    f32x4 acc[4][4] = {};

    const short* Ag = (const short*)A;
    const short* Bg = (const short*)Bm;
    const int srow = lane >> 2;          // 0..15 within a 16-row group
    const int scol = (lane & 3) * 8;     // elem offset 0/8/16/24 (16 B chunks)

    for (int k0 = 0; k0 < D_SZ; k0 += BK) {
        __syncthreads();   // protect previous iteration's fragment reads
        // A: 256 rows = 8 waves x 2 groups of 16
#pragma unroll
        for (int c = 0; c < 2; c++) {
            int row = wave * 32 + c * 16 + srow;
            __builtin_amdgcn_global_load_lds(
                (gvoid*)(Ag + (size_t)(bm + row) * D_SZ + k0 + scol),
                (lvoid*)(As + row * BK + scol), 16, 0, 0);
        }
        // B: 128 rows = 8 waves x 1 group of 16
        {
            int row = wave * 16 + srow;
            __builtin_amdgcn_global_load_lds(
                (gvoid*)(Bg + (size_t)(bn + row) * D_SZ + k0 + scol),
                (lvoid*)(Bs + row * BK + scol), 16, 0, 0);
        }
        __syncthreads();   // drains vmcnt -> LDS tiles complete

        short8v af[4], bf[4];
#pragma unroll
        for (int i = 0; i < 4; i++)
            af[i] = *(const short8v*)(As + (wm + i * 16 + row16) * BK + koff);
#pragma unroll
        for (int j = 0; j < 4; j++)
            bf[j] = *(const short8v*)(Bs + (wn + j * 16 + row16) * BK + koff);
#pragma unroll
        for (int i = 0; i < 4; i++)
#pragma unroll
            for (int j = 0; j < 4; j++)
                acc[i][j] = __builtin_amdgcn_mfma_f32_16x16x32_bf16(af[i], bf[j], acc[i][j], 0, 0, 0);
    }

    // C/D layout: col = lane&15, row = quad*4 + reg  [m89/m91 verified]
    // bm is a multiple of 256 and 8192 % 256 == 0 -> region test stays valid.
    if (bm < B_SZ) {
        // score region: written once, read once by pursuit -> non-temporal
#pragma unroll
        for (int i = 0; i < 4; i++) {
            int grow = bm + wm + i * 16 + quad * 4;
#pragma unroll
            for (int j = 0; j < 4; j++) {
                int gcol = bn + wn + j * 16 + row16;
#pragma unroll
                for (int r = 0; r < 4; r++)
                    __builtin_nontemporal_store((_Float16)acc[i][j][r],
                                                &C[(size_t)(grow + r) * K_SZ + gcol]);
            }
        }
    } else {
        // Gram region: hot random-access data for pursuit -> keep cached
#pragma unroll
        for (int i = 0; i < 4; i++) {
            int grow = bm + wm + i * 16 + quad * 4;
#pragma unroll
            for (int j = 0; j < 4; j++) {
                int gcol = bn + wn + j * 16 + row16;
#pragma unroll
                for (int r = 0; r < 4; r++)
                    C[(size_t)(grow + r) * K_SZ + gcol] = (_Float16)acc[i][j][r];
            }
        }
    }
}

// ---------------------------------------------------------------------------
// Kernel 3: pursuit, wave-per-row, g in LDS as fp16 (8 KB/row, linear,
// conflict-free b128). EXACT round-0 version (best measured: 208 us).
// Latency/concurrency-bound at ~2.8 TB/s effective on 554 MB L2-miss; three
// structural variants (reg-g, 2-wave blocks, 2-chain waves) all regressed.
// ---------------------------------------------------------------------------
#define MAXC 16
#define MARGIN 1.5f

__global__ __launch_bounds__(256, 4)
void pursuit_kernel(const float* __restrict__ targets,
                    const float* __restrict__ codebook,
                    const _Float16* __restrict__ S,   // [12288 x 4096]; rows >=8192 are Gram
                    const double* __restrict__ cn2,   // [4096] exact ||c_k||^2
                    float* __restrict__ out) {
    const int wave = threadIdx.x >> 6;
    const int lane = threadIdx.x & 63;
    const int b = blockIdx.x * 4 + wave;
    const int lane8 = lane * 8;

    __shared__ alignas(16) _Float16 g_s[4][K_SZ];
    __shared__ int s_cnt[4];
    __shared__ int s_cand[4][MAXC];
    _Float16* g = g_s[wave];
    int* cnt  = &s_cnt[wave];
    int* cand = s_cand[wave];

    // ---- init: score row -> LDS (non-temporal), lane max in flight ----
    h2 tmax; tmax[0] = (_Float16)0; tmax[1] = (_Float16)0;
    {
        const _Float16* g0 = S + (size_t)b * K_SZ + lane8;
#pragma unroll
        for (int c = 0; c < 8; c++) {
            half8v h = __builtin_nontemporal_load((const half8v*)(g0 + c * 512));
            *(half8v*)&g[c * 512 + lane8] = h;
            H2x4 u = __builtin_bit_cast(H2x4, h);
            tmax = hmax2(tmax, hmax2(hmax2(habs2(u.a), habs2(u.b)),
                                     hmax2(habs2(u.c), habs2(u.d))));
        }
    }
    float m = fmaxf((float)tmax[0], (float)tmax[1]);

    // ---- lane-private fp64 residual + tn2 (non-temporal target read) ----
    double rres[8];
    double loc = 0.0;
    {
        const float* tg = targets + (size_t)b * D_SZ + lane8;
        f32x4 t0 = __builtin_nontemporal_load((const f32x4*)tg);
        f32x4 t1 = __builtin_nontemporal_load((const f32x4*)(tg + 4));
        rres[0] = t0[0]; rres[1] = t0[1]; rres[2] = t0[2]; rres[3] = t0[3];
        rres[4] = t1[0]; rres[5] = t1[1]; rres[6] = t1[2]; rres[7] = t1[3];
#pragma unroll
        for (int e = 0; e < 8; e++) loc += rres[e] * rres[e];
    }
#pragma unroll
    for (int o = 32; o > 0; o >>= 1) loc += __shfl_xor(loc, o, 64);
    double rn2 = loc;
    const bool tgt_ok = (sqrt(loc) >= 1e-8);

    float* out_seq  = out + (size_t)b * L_SZ;
    float* out_mask = out + (size_t)B_SZ * L_SZ + (size_t)b * L_SZ;
    float* out_res  = out + (size_t)2 * B_SZ * L_SZ + (size_t)b * D_SZ;

    double decay = 1.0;

    for (int t = 0; t < L_SZ; t++) {
        decay *= 0.95;
        bool active = (sqrt(rn2) >= 0.01) && tgt_ok;   // wave-uniform
        if (!active) {                                 // stays inactive forever
            if (lane == 0)
                for (int tt = t; tt < L_SZ; tt++) {
                    __builtin_nontemporal_store(0.0f, &out_seq[tt]);
                    __builtin_nontemporal_store(0.0f, &out_mask[tt]);
                }
            break;
        }

        // ---- wave max + threshold ----
        float M = m;
#pragma unroll
        for (int o = 32; o > 0; o >>= 1) M = fmaxf(M, __shfl_xor(M, o, 64));
        float thr = M - MARGIN;

        // ---- candidate collection: re-read LDS under divergent guard ----
        if (lane == 0) *cnt = 0;
        if (m >= thr) {
#pragma unroll
            for (int c = 0; c < 8; c++) {
                half8v h = *(const half8v*)&g[c * 512 + lane8];
#pragma unroll
                for (int e = 0; e < 8; e++) {
                    float f = fabsf((float)h[e]);
                    if (f >= thr) {
                        int q = atomicAdd(cnt, 1);
                        if (q < MAXC) cand[q] = c * 512 + lane8 + e;
                    }
                }
            }
        }
        __threadfence_block();
        int nc = min(*cnt, MAXC);

        // ---- exact fp64 rescore; Gram loads hoisted off the tail ----
        int bk; double bv;
        float4 c0, c1;
        half8v Gh[8];
        if (nc == 1) {
            bk = __builtin_amdgcn_readfirstlane(cand[0]);
            const float* cr = codebook + (size_t)bk * D_SZ + lane8;
            const _Float16* Gp = S + (size_t)(B_SZ + bk) * K_SZ + lane8;
            c0 = *(const float4*)cr;
            c1 = *(const float4*)(cr + 4);
#pragma unroll
            for (int c = 0; c < 8; c++) Gh[c] = *(const half8v*)(Gp + c * 512);
            double s = rres[0] * (double)c0.x + rres[1] * (double)c0.y
                     + rres[2] * (double)c0.z + rres[3] * (double)c0.w
                     + rres[4] * (double)c1.x + rres[5] * (double)c1.y
                     + rres[6] * (double)c1.z + rres[7] * (double)c1.w;
#pragma unroll
            for (int o = 32; o > 0; o >>= 1) s += __shfl_xor(s, o, 64);
            bv = s;
        } else {
            bk = -1; bv = 0.0;
            for (int ci = 0; ci < nc; ci++) {
                int k = __builtin_amdgcn_readfirstlane(cand[ci]);
                const float* cr = codebook + (size_t)k * D_SZ + lane8;
                float4 d0 = *(const float4*)cr;
                float4 d1 = *(const float4*)(cr + 4);
                double s = rres[0] * (double)d0.x + rres[1] * (double)d0.y
                         + rres[2] * (double)d0.z + rres[3] * (double)d0.w
                         + rres[4] * (double)d1.x + rres[5] * (double)d1.y
                         + rres[6] * (double)d1.z + rres[7] * (double)d1.w;
#pragma unroll
                for (int o = 32; o > 0; o >>= 1) s += __shfl_xor(s, o, 64);
                if (bk < 0 || fabs(s) > fabs(bv) ||
                    (fabs(s) == fabs(bv) && k < bk)) { bk = k; bv = s; }
            }
            const float* cr = codebook + (size_t)bk * D_SZ + lane8;   // winner row
            const _Float16* Gp = S + (size_t)(B_SZ + bk) * K_SZ + lane8;
            c0 = *(const float4*)cr;
            c1 = *(const float4*)(cr + 4);
#pragma unroll
            for (int c = 0; c < 8; c++) Gh[c] = *(const half8v*)(Gp + c * 512);
        }

        // ---- decision + exact ||r||^2 identity + outputs ----
        const double cn2bk = cn2[bk];
        double sd = ((bv >= 0.0) ? 1.0 : -1.0) * decay;
        rn2 = rn2 - 2.0 * sd * bv + sd * sd * cn2bk;
        if (lane == 0) {
            __builtin_nontemporal_store((float)((bv >= 0.0) ? bk : (-bk - 1)), &out_seq[t]);
            __builtin_nontemporal_store(1.0f, &out_mask[t]);
        }
        const float sdf = (float)sd;
        h2 sdh2; sdh2[0] = (_Float16)sdf; sdh2[1] = (_Float16)sdf;

        // ---- fused g update (LDS RMW) + next-step lane max ----
        tmax[0] = (_Float16)0; tmax[1] = (_Float16)0;
#pragma unroll
        for (int c = 0; c < 8; c++) {
            half8v gv = *(const half8v*)&g[c * 512 + lane8];
            H2x4 ug = __builtin_bit_cast(H2x4, gv);
            H2x4 uG = __builtin_bit_cast(H2x4, Gh[c]);
            ug.a -= sdh2 * uG.a; ug.b -= sdh2 * uG.b;
            ug.c -= sdh2 * uG.c; ug.d -= sdh2 * uG.d;
            *(half8v*)&g[c * 512 + lane8] = __builtin_bit_cast(half8v, ug);
            tmax = hmax2(tmax, hmax2(hmax2(habs2(ug.a), habs2(ug.b)),
                                     hmax2(habs2(ug.c), habs2(ug.d))));
        }
        m = fmaxf((float)tmax[0], (float)tmax[1]);

        // ---- exact diagonal patch: g[bk] := fp16(bv - sd*||c_bk||^2).
        //      m may be stale-high by <=0.5 on one lane; MARGIN=1.5 covers it,
        //      and the candidate re-read above sees the patched value. ----
        if (lane == 0) g[bk] = (_Float16)(float)(bv - sd * cn2bk);

        // ---- exact fp64 residual update (winner row already in regs) ----
        rres[0] -= sd * (double)c0.x; rres[1] -= sd * (double)c0.y;
        rres[2] -= sd * (double)c0.z; rres[3] -= sd * (double)c0.w;
        rres[4] -= sd * (double)c1.x; rres[5] -= sd * (double)c1.y;
        rres[6] -= sd * (double)c1.z; rres[7] -= sd * (double)c1.w;
    }

    // ---- final residual (non-temporal) ----
    {
        f32x4 r0, r1;
        r0[0] = (float)rres[0]; r0[1] = (float)rres[1]; r0[2] = (float)rres[2]; r0[3] = (float)rres[3];
        r1[0] = (float)rres[4]; r1[1] = (float)rres[5]; r1[2] = (float)rres[6]; r1[3] = (float)rres[7];
        __builtin_nontemporal_store(r0, (f32x4*)(out_res + lane8));
        __builtin_nontemporal_store(r1, (f32x4*)(out_res + lane8 + 4));
    }
}

// ---------------------------------------------------------------------------
extern "C" void kernel_launch(void* const* d_in, const int* in_sizes, int n_in,
                              void* d_out, int out_size, void* d_ws, size_t ws_size,
                              hipStream_t stream) {
    const float* targets  = (const float*)d_in[0];
    const float* codebook = (const float*)d_in[1];
    float* out = (float*)d_out;

    __hip_bfloat16* abf = (__hip_bfloat16*)d_ws;                         // 12,582,912 B
    _Float16* S = (_Float16*)((char*)d_ws + (size_t)M_ALL * D_SZ * 2);   // 100,663,296 B
    double* cn2 = (double*)((char*)d_ws + (size_t)M_ALL * D_SZ * 2
                                        + (size_t)M_ALL * K_SZ * 2);     // 32,768 B
    // total ws needed: ~113.3 MB

    int total4 = (M_ALL * D_SZ) / 4;
    cast_bf16_kernel<<<(total4 + 255) / 256, 256, 0, stream>>>(targets, codebook, abf);
    cn2_kernel<<<K_SZ / 4, 256, 0, stream>>>(codebook, cn2);

    dim3 ggrid(K_SZ / BN, M_ALL / BM);   // 32 x 48 = 1536 blocks of 512 threads
    gemm_bt_kernel<<<ggrid, 512, 0, stream>>>(abf, abf + (size_t)B_SZ * D_SZ, S);

    pursuit_kernel<<<B_SZ / 4, 256, 0, stream>>>(targets, codebook, S, cn2, out);
}